// Round 12
// baseline (782.767 us; speedup 1.0000x reference)
//
#include <hip/hip_runtime.h>
#include <hip/hip_bf16.h>
#include <stdint.h>

// CrossStreamAttention: B=32768, D=512, H=8, S=3, DH=64
// R11: R10 + gemm_ln — gemm<F32> and lnorm fused into one kernel with a
// 64x512 tile (full output row per block): 512 thr = 8 waves (1x8), per-wave
// 64x64 = acc[4][4], LDS As 8K + Bs 64K + stats 4K = 76KB -> 2 blocks/CU
// (16 waves/CU, same occupancy class as gemm_bt). Epilogue: per-row
// (sum,sumsq) -> shfl over lane&15 -> per-wave partials in LDS -> sync ->
// mean/rstd -> write normalized f32 out directly. Saves lnorm's 128 MB pass
// + launch. qkv_attn/gemm_bt(RES,SILU)/gate3/cvtall unchanged from R10
// (774.4us, qkv 151.7).

typedef float f32x4 __attribute__((ext_vector_type(4)));
typedef short bf16x8 __attribute__((ext_vector_type(8)));  // 8 bf16 in 4 VGPRs

__device__ __forceinline__ float bf2f(unsigned short h) {
  return __uint_as_float(((unsigned)h) << 16);
}
// native RNE convert (v_cvt_pk_bf16_f32 class)
__device__ __forceinline__ unsigned short f2bf(float f) {
  __hip_bfloat16 h = __float2bfloat16(f);
  return *reinterpret_cast<unsigned short*>(&h);
}
// packed pair: lo in low 16 bits, hi in high 16 bits (one v_cvt_pk_bf16_f32)
__device__ __forceinline__ unsigned pack2bf(float lo, float hi) {
  __hip_bfloat162 h2 = __float22bfloat162_rn(make_float2(lo, hi));
  return *reinterpret_cast<unsigned*>(&h2);
}
__device__ __forceinline__ uint2 f2bf4p(float4 v) {
  return make_uint2(pack2bf(v.x, v.y), pack2bf(v.z, v.w));
}

__device__ __forceinline__ void async_cp16(const void* g, void* lds) {
  __builtin_amdgcn_global_load_lds(
      (const __attribute__((address_space(1))) void*)g,
      (__attribute__((address_space(3))) void*)lds, 16, 0, 0);
}

// ---------------------------------------------------------------- converts
// all four weight tensors in one launch; dst segments are contiguous in ws.
__global__ void __launch_bounds__(256) cvtall(const float4* __restrict__ w_in,
                                              const float4* __restrict__ w_out,
                                              const float4* __restrict__ w1,
                                              const float4* __restrict__ w2,
                                              uint2* __restrict__ dst) {
  int i = blockIdx.x * 256 + threadIdx.x;   // 0..786431
  const float4* s;
  int off;
  if (i < 196608)      { s = w_in;  off = 0; }
  else if (i < 262144) { s = w_out; off = 196608; }
  else if (i < 655360) { s = w1;    off = 262144; }
  else                 { s = w2;    off = 655360; }
  dst[i] = f2bf4p(s[i - off]);
}

// ---------------------------------------------------------------- fused QKV gemm + attention
// grid (8, ny). Logical tile: 96 rows (32 b's) x 192 cols (q|k|v of head h).
// XCD-grouped remap: hw id = y*8+x; xcd = id&7; j = id>>3; h = j&7;
// panel = xcd*(ny/8) + (j>>3)  ->  8 consecutive blocks on one XCD share one
// A-panel (f32 inputs fetched once, L2-served 7x). ny % 8 == 0 required.
// A staging: reg-staged from f32 (prefetch issue after barrier[2], convert +
// ds_write at top of next iter). B staging: global_load_lds as before.
// Block h side-writes the k0==h*64 slice of stacked bf16 S (balanced).
__global__ void __launch_bounds__(256)
qkv_attn(const float* __restrict__ X0,          // kin  [Bc,512] f32
         const float* __restrict__ X1,          // colr
         const float* __restrict__ X2,          // spi
         const unsigned short* __restrict__ Wi, // [1536,512] bf16
         const float* __restrict__ bin,         // [1536]
         unsigned short* __restrict__ Sout,     // [3Bc,512] bf16 side-product
         unsigned short* __restrict__ AO) {     // [3Bc,512] bf16
  __shared__ unsigned short lds[96 * 200];      // 38400 B; union staging/C
  unsigned short* Abuf = lds;                   // [96][64] during K-loop
  unsigned short* Bbuf = lds + 6144;            // [192][64] during K-loop

  const int t = threadIdx.x;
  const int lane = t & 63;
  const int wave = t >> 6;
  const int wm = wave >> 1, wn = wave & 1;

  const int ny = gridDim.y;
  const int id = blockIdx.y * 8 + blockIdx.x;
  const int xcd = id & 7, j = id >> 3;
  const int h = j & 7;
  const long m0 = (long)(xcd * (ny >> 3) + (j >> 3)) * 96;

  const int trow = t >> 3;                      // 0..31 within a 32-row round
  const int swz = ((t & 7) ^ (trow & 7)) << 3;  // element offset
  // A rows rr = m0 + trow + 32r; m0 % 3 == 0 -> b = m0/3 + rl/3, s = rl%3
  const long b0 = m0 / 3;
  const float* Aptr[3];
  unsigned short* Sptr[3];
#pragma unroll
  for (int r = 0; r < 3; r++) {
    const int rl = trow + 32 * r;
    const int br = rl / 3;
    const int sr = rl - 3 * br;
    const float* X = (sr == 0) ? X0 : (sr == 1) ? X1 : X2;
    Aptr[r] = X + (b0 + br) * 512 + swz;
    Sptr[r] = Sout + (m0 + rl) * 512 + swz;
  }
  const unsigned short* Bg = Wi + ((long)h * 64 + trow) * 512 + swz;
  unsigned short* AsD = Abuf + t * 8;
  unsigned short* BsD = Bbuf + t * 8;

  f32x4 acc[3][6] = {};
  const int arow0 = wm * 48 + (lane & 15);
  const int brow0 = wn * 96 + (lane & 15);

  // prefetch A(k0=0) into f32 regs
  float4 Alo[3], Ahi[3];
#pragma unroll
  for (int r = 0; r < 3; r++) {
    Alo[r] = *(const float4*)(Aptr[r]);
    Ahi[r] = *(const float4*)(Aptr[r] + 4);
  }

  for (int k0 = 0; k0 < 512; k0 += 64) {
    __syncthreads();
    // convert prefetched A, commit to LDS; block h writes its own k-slice of S
    const bool sw = ((k0 >> 6) == h);
#pragma unroll
    for (int r = 0; r < 3; r++) {
      const uint4 uv = make_uint4(
          pack2bf(Alo[r].x, Alo[r].y), pack2bf(Alo[r].z, Alo[r].w),
          pack2bf(Ahi[r].x, Ahi[r].y), pack2bf(Ahi[r].z, Ahi[r].w));
      *(uint4*)(AsD + r * 2048) = uv;
      if (sw) *(uint4*)(Sptr[r] + k0) = uv;
    }
#pragma unroll
    for (int r = 0; r < 6; r++)
      async_cp16(Bg + (long)((r >> 1) * 512 + (r & 1) * 32) * 512 + k0, BsD + r * 2048);
    __syncthreads();
    // issue next A loads now — overlap with the MFMA phase below
    if (k0 + 64 < 512) {
#pragma unroll
      for (int r = 0; r < 3; r++) {
        Alo[r] = *(const float4*)(Aptr[r] + k0 + 64);
        Ahi[r] = *(const float4*)(Aptr[r] + k0 + 68);
      }
    }
#pragma unroll
    for (int kk = 0; kk < 2; kk++) {
      const int sc = ((kk * 4 + (lane >> 4)) ^ (lane & 7)) << 3;
      bf16x8 af[3], bfr[6];
#pragma unroll
      for (int mt = 0; mt < 3; mt++)
        af[mt] = *(const bf16x8*)&Abuf[(arow0 + mt * 16) * 64 + sc];
#pragma unroll
      for (int nt = 0; nt < 6; nt++)
        bfr[nt] = *(const bf16x8*)&Bbuf[(brow0 + nt * 16) * 64 + sc];
#pragma unroll
      for (int mt = 0; mt < 3; mt++)
#pragma unroll
        for (int nt = 0; nt < 6; nt++)
          acc[mt][nt] = __builtin_amdgcn_mfma_f32_16x16x32_bf16(
              af[mt], bfr[nt], acc[mt][nt], 0, 0, 0);
    }
  }

  // dump C (+bias) as bf16 into LDS, stride 200 — packed converts
  __syncthreads();
  const int crow0 = wm * 48 + ((lane >> 4) << 2);
  const int ccol0 = wn * 96 + (lane & 15);
#pragma unroll
  for (int nt = 0; nt < 6; nt++) {
    const int col = ccol0 + nt * 16;                 // 0..191
    const float bv = bin[(col >> 6) * 512 + h * 64 + (col & 63)];
#pragma unroll
    for (int mt = 0; mt < 3; mt++) {
      const int rb = (crow0 + mt * 16) * 200 + col;
      const unsigned p01 = pack2bf(acc[mt][nt][0] + bv, acc[mt][nt][1] + bv);
      const unsigned p23 = pack2bf(acc[mt][nt][2] + bv, acc[mt][nt][3] + bv);
      lds[rb]       = (unsigned short)p01;
      lds[rb + 200] = (unsigned short)(p01 >> 16);
      lds[rb + 400] = (unsigned short)p23;
      lds[rb + 600] = (unsigned short)(p23 >> 16);
    }
  }
  __syncthreads();

  // attention: wave handles 8 b's; lane = bi*8 + l8; lane owns d = l8*8..+7
  const int bi = lane >> 3;                          // 0..7 (b within wave's 8)
  const int l8 = lane & 7;
  const int r0 = (wave * 8 + bi) * 3;                // local row of stream 0
  float q[3][8], k[3][8], v[3][8];
#pragma unroll
  for (int s = 0; s < 3; s++) {
    const unsigned short* rowp = &lds[(r0 + s) * 200 + l8 * 8];
    uint4 qu = *(const uint4*)(rowp);
    uint4 ku = *(const uint4*)(rowp + 64);
    uint4 vu = *(const uint4*)(rowp + 128);
    const unsigned* qw = (const unsigned*)&qu;
    const unsigned* kw = (const unsigned*)&ku;
    const unsigned* vw = (const unsigned*)&vu;
#pragma unroll
    for (int jj = 0; jj < 4; jj++) {
      q[s][2 * jj]     = __uint_as_float(qw[jj] << 16);
      q[s][2 * jj + 1] = __uint_as_float(qw[jj] & 0xffff0000u);
      k[s][2 * jj]     = __uint_as_float(kw[jj] << 16);
      k[s][2 * jj + 1] = __uint_as_float(kw[jj] & 0xffff0000u);
      v[s][2 * jj]     = __uint_as_float(vw[jj] << 16);
      v[s][2 * jj + 1] = __uint_as_float(vw[jj] & 0xffff0000u);
    }
  }
  float p[3][3];
#pragma unroll
  for (int s = 0; s < 3; s++)
#pragma unroll
    for (int u = 0; u < 3; u++) {
      float d = 0.f;
#pragma unroll
      for (int e = 0; e < 8; e++) d = fmaf(q[s][e], k[u][e], d);
      p[s][u] = d;
    }
#pragma unroll
  for (int m = 1; m < 8; m <<= 1)
#pragma unroll
    for (int s = 0; s < 3; s++)
#pragma unroll
      for (int u = 0; u < 3; u++) p[s][u] += __shfl_xor(p[s][u], m, 64);

  unsigned short* ob = AO + (m0 + r0) * 512 + h * 64 + l8 * 8;
#pragma unroll
  for (int s = 0; s < 3; s++) {
    float a0 = p[s][0] * 0.125f, a1 = p[s][1] * 0.125f, a2 = p[s][2] * 0.125f;
    float mx = fmaxf(a0, fmaxf(a1, a2));
    float e0 = __expf(a0 - mx), e1 = __expf(a1 - mx), e2 = __expf(a2 - mx);
    float inv = 1.0f / (e0 + e1 + e2);
    unsigned ow[4];
#pragma unroll
    for (int jj = 0; jj < 4; jj++) {
      float lo = (e0 * v[0][2 * jj] + e1 * v[1][2 * jj] + e2 * v[2][2 * jj]) * inv;
      float hi = (e0 * v[0][2 * jj + 1] + e1 * v[1][2 * jj + 1] + e2 * v[2][2 * jj + 1]) * inv;
      ow[jj] = pack2bf(lo, hi);
    }
    *(uint4*)(ob + s * 512) = *(uint4*)ow;
  }
}

// ---------------------------------------------------------------- GEMM
// C[M,N] = A[M,K] @ W[N,K]^T + bias. 128x128 tile, BK=64, 4 waves (2x2),
// each wave 64x64 via 4x4 grid of 16x16x32 bf16 MFMA. XCD-grouped swizzle.
enum { EPI_BF16 = 0, EPI_RES = 1, EPI_SILU = 2, EPI_F32 = 3 };

template <int EPI>
__global__ void __launch_bounds__(256)
gemm_bt(const unsigned short* __restrict__ A,
        const unsigned short* __restrict__ W,
        const float* __restrict__ bias,
        const unsigned short* __restrict__ Res,
        void* __restrict__ Out,
        int K, int N) {
  __shared__ unsigned short As[128 * 64];
  __shared__ unsigned short Bs[128 * 64];
  const int t = threadIdx.x;
  const int lane = t & 63;
  const int wave = t >> 6;
  const int wm = wave >> 1, wn = wave & 1;

  const int nb = gridDim.x;
  const int nblocks = nb * gridDim.y;
  const int id = blockIdx.y * nb + blockIdx.x;
  const int lid = ((nblocks & 7) == 0) ? ((id & 7) * (nblocks >> 3) + (id >> 3)) : id;
  const long bm = (long)(lid / nb) * 128;
  const long bn = (long)(lid % nb) * 128;

  const int srow = t >> 3;
  const int schunk = ((t & 7) ^ (srow & 7)) << 3;  // element offset
  const unsigned short* Ag = A + (bm + srow) * (long)K + schunk;
  const unsigned short* Wg = W + (bn + srow) * (long)K + schunk;
  unsigned short* AsD = As + t * 8;
  unsigned short* BsD = Bs + t * 8;

  f32x4 acc[4][4] = {};
  const int arow0 = wm * 64 + (lane & 15);
  const int brow0 = wn * 64 + (lane & 15);

  for (int k0 = 0; k0 < K; k0 += 64) {
    __syncthreads();
#pragma unroll
    for (int i = 0; i < 4; i++) {
      async_cp16(Ag + (long)(i * 32) * K + k0, AsD + i * 2048);
      async_cp16(Wg + (long)(i * 32) * K + k0, BsD + i * 2048);
    }
    __syncthreads();
#pragma unroll
    for (int kk = 0; kk < 2; kk++) {
      const int sc = ((kk * 4 + (lane >> 4)) ^ (lane & 7)) << 3;
      bf16x8 af[4], bfr[4];
#pragma unroll
      for (int mt = 0; mt < 4; mt++)
        af[mt] = *(const bf16x8*)&As[(arow0 + mt * 16) * 64 + sc];
#pragma unroll
      for (int nt = 0; nt < 4; nt++)
        bfr[nt] = *(const bf16x8*)&Bs[(brow0 + nt * 16) * 64 + sc];
#pragma unroll
      for (int mt = 0; mt < 4; mt++)
#pragma unroll
        for (int nt = 0; nt < 4; nt++)
          acc[mt][nt] = __builtin_amdgcn_mfma_f32_16x16x32_bf16(
              af[mt], bfr[nt], acc[mt][nt], 0, 0, 0);
    }
  }

  // C/D layout: col = lane&15, row = (lane>>4)*4 + r
  const long row0 = bm + wm * 64 + ((lane >> 4) << 2);
  const int col0 = (int)bn + wn * 64 + (lane & 15);
#pragma unroll
  for (int nt = 0; nt < 4; nt++) {
    const int col = col0 + nt * 16;
    const float bv = bias[col];
#pragma unroll
    for (int mt = 0; mt < 4; mt++) {
      const long rbase = row0 + mt * 16;
#pragma unroll
      for (int r = 0; r < 4; r++) {
        float v = acc[mt][nt][r] + bv;
        const long idx = (rbase + r) * (long)N + col;
        if (EPI == EPI_RES) v += bf2f(Res[idx]);
        if (EPI == EPI_SILU) v = v * (1.0f / (1.0f + __expf(-v)));
        if (EPI == EPI_F32)
          ((float*)Out)[idx] = v;
        else
          ((unsigned short*)Out)[idx] = f2bf(v);
      }
    }
  }
}

// ---------------------------------------------------------------- GEMM + LayerNorm fused
// out[M,512] = LN(A[M,1024] @ W2[512,1024]^T + b2) * gamma + beta, f32 out.
// 64x512 tile (full row per block): 512 thr = 8 waves (1x8), per-wave 64x64
// = acc[4][4]. LDS: As 8K + Bs 64K + stats 4K = 76KB -> 2 blocks/CU.
__global__ void __launch_bounds__(512)
gemm_ln(const unsigned short* __restrict__ A,    // [M,1024] bf16
        const unsigned short* __restrict__ W,    // [512,1024] bf16
        const float* __restrict__ bias,          // [512]
        const float* __restrict__ gamma,         // [512]
        const float* __restrict__ beta,          // [512]
        float* __restrict__ Out,                 // [M,512] f32
        int K) {
  __shared__ unsigned short As[64 * 64];         // 8 KB
  __shared__ unsigned short Bs[512 * 64];        // 64 KB
  __shared__ float stats[8][64][2];              // 4 KB
  const int t = threadIdx.x;
  const int lane = t & 63;
  const int wave = t >> 6;                       // wn 0..7

  const int nblocks = gridDim.x;
  const int id = blockIdx.x;
  const int lid = ((nblocks & 7) == 0) ? ((id & 7) * (nblocks >> 3) + (id >> 3)) : id;
  const long bm = (long)lid * 64;

  const int srow = t >> 3;                       // 0..63
  const int sch = ((t & 7) ^ (srow & 7)) << 3;
  const unsigned short* Ag = A + (bm + srow) * (long)K + sch;
  const unsigned short* Wg = W + (long)srow * K + sch;
  unsigned short* AsD = As + t * 8;
  unsigned short* BsD = Bs + t * 8;

  f32x4 acc[4][4] = {};
  const int arow0 = lane & 15;
  const int brow0 = wave * 64 + (lane & 15);

  for (int k0 = 0; k0 < K; k0 += 64) {
    __syncthreads();
    async_cp16(Ag + k0, AsD);                    // A: 64 rows in one round
#pragma unroll
    for (int i = 0; i < 8; i++)                  // B: 512 rows in 8 rounds
      async_cp16(Wg + (long)(i * 64) * K + k0, BsD + i * 4096);
    __syncthreads();
#pragma unroll
    for (int kk = 0; kk < 2; kk++) {
      const int sc = ((kk * 4 + (lane >> 4)) ^ (lane & 7)) << 3;
      bf16x8 af[4], bfr[4];
#pragma unroll
      for (int mt = 0; mt < 4; mt++)
        af[mt] = *(const bf16x8*)&As[(arow0 + mt * 16) * 64 + sc];
#pragma unroll
      for (int nt = 0; nt < 4; nt++)
        bfr[nt] = *(const bf16x8*)&Bs[(brow0 + nt * 16) * 64 + sc];
#pragma unroll
      for (int mt = 0; mt < 4; mt++)
#pragma unroll
        for (int nt = 0; nt < 4; nt++)
          acc[mt][nt] = __builtin_amdgcn_mfma_f32_16x16x32_bf16(
              af[mt], bfr[nt], acc[mt][nt], 0, 0, 0);
    }
  }

  // epilogue: bias + per-row stats -> LDS -> LN -> write f32 out
  const int colb = wave * 64 + (lane & 15);      // + nt*16
  float bv[4], gm[4], be[4];
#pragma unroll
  for (int nt = 0; nt < 4; nt++) {
    bv[nt] = bias[colb + nt * 16];
    gm[nt] = gamma[colb + nt * 16];
    be[nt] = beta[colb + nt * 16];
  }
  // per-row partials: row rl = mt*16 + (lane>>4)*4 + r
#pragma unroll
  for (int mt = 0; mt < 4; mt++)
#pragma unroll
    for (int r = 0; r < 4; r++) {
      float s = 0.f, ss = 0.f;
#pragma unroll
      for (int nt = 0; nt < 4; nt++) {
        const float v = acc[mt][nt][r] + bv[nt];
        s += v; ss += v * v;
      }
#pragma unroll
      for (int m = 1; m < 16; m <<= 1) {
        s += __shfl_xor(s, m, 64);
        ss += __shfl_xor(ss, m, 64);
      }
      if ((lane & 15) == 0) {
        const int rl = mt * 16 + ((lane >> 4) << 2) + r;
        stats[wave][rl][0] = s;
        stats[wave][rl][1] = ss;
      }
    }
  __syncthreads();
#pragma unroll
  for (int mt = 0; mt < 4; mt++)
#pragma unroll
    for (int r = 0; r < 4; r++) {
      const int rl = mt * 16 + ((lane >> 4) << 2) + r;
      float s = 0.f, ss = 0.f;
#pragma unroll
      for (int w = 0; w < 8; w++) {
        s += stats[w][rl][0];
        ss += stats[w][rl][1];
      }
      const float mean = s * (1.0f / 512.0f);
      const float var = ss * (1.0f / 512.0f) - mean * mean;
      const float rstd = rsqrtf(var + 1e-5f);
      float* orow = Out + (bm + rl) * 512;
#pragma unroll
      for (int nt = 0; nt < 4; nt++) {
        const float v = acc[mt][nt][r] + bv[nt];
        orow[colb + nt * 16] = (v - mean) * rstd * gm[nt] + be[nt];
      }
    }
}

// ---------------------------------------------------------------- gate
// one wave per batch row, ushort8 loads; in-place safe (each wave reads only
// the elements it writes, all reads precede all writes).
__global__ void __launch_bounds__(256) gate3(const unsigned short* AT,
                                             const float* __restrict__ WG,
                                             const float* __restrict__ BG,
                                             unsigned short* G) {
  int row = blockIdx.x * 4 + (threadIdx.x >> 6);
  int lane = threadIdx.x & 63;
  const unsigned short* rp = AT + (long)row * 1536 + lane * 8;
  float x[3][8];
  float p[3] = {0.f, 0.f, 0.f};
#pragma unroll
  for (int seg = 0; seg < 3; seg++) {
    uint4 u = *(const uint4*)(rp + seg * 512);
    const unsigned* uw = (const unsigned*)&u;
#pragma unroll
    for (int j = 0; j < 4; j++) {
      x[seg][2 * j]     = __uint_as_float(uw[j] << 16);
      x[seg][2 * j + 1] = __uint_as_float(uw[j] & 0xffff0000u);
    }
    const int e0 = seg * 512 + lane * 8;
#pragma unroll
    for (int g = 0; g < 3; g++) {
      const float* wp = WG + g * 1536 + e0;
#pragma unroll
      for (int e = 0; e < 8; e++) p[g] = fmaf(x[seg][e], wp[e], p[g]);
    }
  }
#pragma unroll
  for (int m = 1; m < 64; m <<= 1)
#pragma unroll
    for (int g = 0; g < 3; g++) p[g] += __shfl_xor(p[g], m, 64);
  float g0 = p[0] + BG[0], g1 = p[1] + BG[1], g2 = p[2] + BG[2];
  float mx = fmaxf(g0, fmaxf(g1, g2));
  g0 = __expf(g0 - mx); g1 = __expf(g1 - mx); g2 = __expf(g2 - mx);
  float inv = 1.0f / (g0 + g1 + g2);
  float gs[3] = {g0 * inv, g1 * inv, g2 * inv};
  unsigned short* op = G + (long)row * 1536 + lane * 8;
#pragma unroll
  for (int seg = 0; seg < 3; seg++) {
    unsigned ow[4];
#pragma unroll
    for (int j = 0; j < 4; j++)
      ow[j] = pack2bf(x[seg][2 * j] * gs[seg], x[seg][2 * j + 1] * gs[seg]);
    *(uint4*)(op + seg * 512) = *(uint4*)ow;
  }
}

// ---------------------------------------------------------------- launch
extern "C" void kernel_launch(void* const* d_in, const int* in_sizes, int n_in,
                              void* d_out, int out_size, void* d_ws, size_t ws_size,
                              hipStream_t stream) {
  const float* kin    = (const float*)d_in[0];
  const float* colr   = (const float*)d_in[1];
  const float* spi    = (const float*)d_in[2];
  const float* w_in   = (const float*)d_in[3];
  const float* b_in   = (const float*)d_in[4];
  const float* w_out  = (const float*)d_in[5];
  const float* b_out  = (const float*)d_in[6];
  const float* w_gate = (const float*)d_in[7];
  const float* b_gate = (const float*)d_in[8];
  const float* w1     = (const float*)d_in[9];
  const float* b1     = (const float*)d_in[10];
  const float* w2     = (const float*)d_in[11];
  const float* b2     = (const float*)d_in[12];
  const float* gamma  = (const float*)d_in[13];
  const float* beta   = (const float*)d_in[14];
  float* out = (float*)d_out;

  // scratch: weights 6,291,456 + S/AO/AT = 9216*Bc (gate in-place)
  long Bc = 32768;
  while (Bc > 1024 && (size_t)(6291456 + 9216 * Bc) > ws_size) Bc >>= 1;
  const int nch = (int)(32768 / Bc);

  char* ws = (char*)d_ws;
  unsigned short* Wic = (unsigned short*)(ws);              // w_in  1536x512
  unsigned short* Woc = (unsigned short*)(ws + 1572864);    // w_out 512x512
  unsigned short* W1c = (unsigned short*)(ws + 2097152);    // w1    1024x1536
  unsigned short* W2c = (unsigned short*)(ws + 5242880);    // w2    512x1024
  char* Sb  = ws + 6291456;                                 // S  [3Bc,512] bf16
  char* AOb = Sb + 3072 * Bc;                               // AO [3Bc,512] bf16
  char* ATb = AOb + 3072 * Bc;                              // AT [3Bc,512] bf16

  cvtall<<<3072, 256, 0, stream>>>((const float4*)w_in, (const float4*)w_out,
                                   (const float4*)w1, (const float4*)w2,
                                   (uint2*)ws);

  for (int c = 0; c < nch; c++) {
    const long boff = (long)c * Bc;
    unsigned short* S_c  = (unsigned short*)Sb;
    unsigned short* AO_c = (unsigned short*)AOb;
    unsigned short* AT_c = (unsigned short*)ATb;
    unsigned short* G_c  = AT_c;                   // gate in-place
    unsigned short* H_c  = (unsigned short*)AOb;   // [Bc,1024], AO dead after proj

    // fused pack + qkv-gemm + attention: f32 inputs -> AO (+ S side-product)
    qkv_attn<<<dim3(8, (int)(Bc / 32)), 256, 0, stream>>>(
        kin + boff * 512, colr + boff * 512, spi + boff * 512,
        Wic, b_in, S_c, AO_c);
    // attn_out = S + AO @ w_out^T + b_out   M=3Bc N=512 K=512
    gemm_bt<EPI_RES><<<dim3(4, (int)(3 * Bc / 128)), 256, 0, stream>>>(
        AO_c, Woc, b_out, S_c, AT_c, 512, 512);
    gate3<<<(int)(Bc / 4), 256, 0, stream>>>(AT_c, w_gate, b_gate, G_c);
    // h = silu(G @ w1^T + b1)           M=Bc N=1024 K=1536
    gemm_bt<EPI_SILU><<<dim3(8, (int)(Bc / 128)), 256, 0, stream>>>(
        G_c, W1c, b1, nullptr, H_c, 1536, 1024);
    // out = LN(h @ w2^T + b2)           M=Bc N=512 K=1024, fused layernorm
    gemm_ln<<<(int)(Bc / 64), 512, 0, stream>>>(
        H_c, W2c, b2, gamma, beta, out + boff * 512, 1024);
  }
}

// Round 13
// 746.104 us; speedup vs baseline: 1.0491x; 1.0491x over previous
//
#include <hip/hip_runtime.h>
#include <hip/hip_bf16.h>
#include <stdint.h>

// CrossStreamAttention: B=32768, D=512, H=8, S=3, DH=64
// R12: R11 + gemm_silu256 — the SILU GEMM (M=32768,N=1024,K=1536) moves to a
// 256x256 8-wave deep-pipelined schedule: K-half (32-elem) LDS half-tiles,
// 4 phases/K-tile {ds_reads; 1 half-tile stage; barrier; lgkmcnt(0);
// setprio(1); 16 MFMA; setprio(0); [vmcnt(8) @p2/p4]; barrier}. Stage targets
// retire 1+ phase before overwrite (K-half split makes this possible; M-half
// tiles are live all 4 phases). 4-6 phases of load flight time; vmcnt never
// 0 in loop. RES stays gemm_bt (NT=8, prologue-dominated), LN stays gemm_ln.

typedef float f32x4 __attribute__((ext_vector_type(4)));
typedef short bf16x8 __attribute__((ext_vector_type(8)));  // 8 bf16 in 4 VGPRs

__device__ __forceinline__ float bf2f(unsigned short h) {
  return __uint_as_float(((unsigned)h) << 16);
}
__device__ __forceinline__ unsigned short f2bf(float f) {
  __hip_bfloat16 h = __float2bfloat16(f);
  return *reinterpret_cast<unsigned short*>(&h);
}
__device__ __forceinline__ unsigned pack2bf(float lo, float hi) {
  __hip_bfloat162 h2 = __float22bfloat162_rn(make_float2(lo, hi));
  return *reinterpret_cast<unsigned*>(&h2);
}
__device__ __forceinline__ uint2 f2bf4p(float4 v) {
  return make_uint2(pack2bf(v.x, v.y), pack2bf(v.z, v.w));
}

__device__ __forceinline__ void async_cp16(const void* g, void* lds) {
  __builtin_amdgcn_global_load_lds(
      (const __attribute__((address_space(1))) void*)g,
      (__attribute__((address_space(3))) void*)lds, 16, 0, 0);
}

// ---------------------------------------------------------------- converts
__global__ void __launch_bounds__(256) cvtall(const float4* __restrict__ w_in,
                                              const float4* __restrict__ w_out,
                                              const float4* __restrict__ w1,
                                              const float4* __restrict__ w2,
                                              uint2* __restrict__ dst) {
  int i = blockIdx.x * 256 + threadIdx.x;   // 0..786431
  const float4* s;
  int off;
  if (i < 196608)      { s = w_in;  off = 0; }
  else if (i < 262144) { s = w_out; off = 196608; }
  else if (i < 655360) { s = w1;    off = 262144; }
  else                 { s = w2;    off = 655360; }
  dst[i] = f2bf4p(s[i - off]);
}

// ---------------------------------------------------------------- fused QKV gemm + attention
__global__ void __launch_bounds__(256)
qkv_attn(const float* __restrict__ X0,          // kin  [Bc,512] f32
         const float* __restrict__ X1,          // colr
         const float* __restrict__ X2,          // spi
         const unsigned short* __restrict__ Wi, // [1536,512] bf16
         const float* __restrict__ bin,         // [1536]
         unsigned short* __restrict__ Sout,     // [3Bc,512] bf16 side-product
         unsigned short* __restrict__ AO) {     // [3Bc,512] bf16
  __shared__ unsigned short lds[96 * 200];      // 38400 B; union staging/C
  unsigned short* Abuf = lds;                   // [96][64] during K-loop
  unsigned short* Bbuf = lds + 6144;            // [192][64] during K-loop

  const int t = threadIdx.x;
  const int lane = t & 63;
  const int wave = t >> 6;
  const int wm = wave >> 1, wn = wave & 1;

  const int ny = gridDim.y;
  const int id = blockIdx.y * 8 + blockIdx.x;
  const int xcd = id & 7, j = id >> 3;
  const int h = j & 7;
  const long m0 = (long)(xcd * (ny >> 3) + (j >> 3)) * 96;

  const int trow = t >> 3;
  const int swz = ((t & 7) ^ (trow & 7)) << 3;
  const long b0 = m0 / 3;
  const float* Aptr[3];
  unsigned short* Sptr[3];
#pragma unroll
  for (int r = 0; r < 3; r++) {
    const int rl = trow + 32 * r;
    const int br = rl / 3;
    const int sr = rl - 3 * br;
    const float* X = (sr == 0) ? X0 : (sr == 1) ? X1 : X2;
    Aptr[r] = X + (b0 + br) * 512 + swz;
    Sptr[r] = Sout + (m0 + rl) * 512 + swz;
  }
  const unsigned short* Bg = Wi + ((long)h * 64 + trow) * 512 + swz;
  unsigned short* AsD = Abuf + t * 8;
  unsigned short* BsD = Bbuf + t * 8;

  f32x4 acc[3][6] = {};
  const int arow0 = wm * 48 + (lane & 15);
  const int brow0 = wn * 96 + (lane & 15);

  float4 Alo[3], Ahi[3];
#pragma unroll
  for (int r = 0; r < 3; r++) {
    Alo[r] = *(const float4*)(Aptr[r]);
    Ahi[r] = *(const float4*)(Aptr[r] + 4);
  }

  for (int k0 = 0; k0 < 512; k0 += 64) {
    __syncthreads();
    const bool sw = ((k0 >> 6) == h);
#pragma unroll
    for (int r = 0; r < 3; r++) {
      const uint4 uv = make_uint4(
          pack2bf(Alo[r].x, Alo[r].y), pack2bf(Alo[r].z, Alo[r].w),
          pack2bf(Ahi[r].x, Ahi[r].y), pack2bf(Ahi[r].z, Ahi[r].w));
      *(uint4*)(AsD + r * 2048) = uv;
      if (sw) *(uint4*)(Sptr[r] + k0) = uv;
    }
#pragma unroll
    for (int r = 0; r < 6; r++)
      async_cp16(Bg + (long)((r >> 1) * 512 + (r & 1) * 32) * 512 + k0, BsD + r * 2048);
    __syncthreads();
    if (k0 + 64 < 512) {
#pragma unroll
      for (int r = 0; r < 3; r++) {
        Alo[r] = *(const float4*)(Aptr[r] + k0 + 64);
        Ahi[r] = *(const float4*)(Aptr[r] + k0 + 68);
      }
    }
#pragma unroll
    for (int kk = 0; kk < 2; kk++) {
      const int sc = ((kk * 4 + (lane >> 4)) ^ (lane & 7)) << 3;
      bf16x8 af[3], bfr[6];
#pragma unroll
      for (int mt = 0; mt < 3; mt++)
        af[mt] = *(const bf16x8*)&Abuf[(arow0 + mt * 16) * 64 + sc];
#pragma unroll
      for (int nt = 0; nt < 6; nt++)
        bfr[nt] = *(const bf16x8*)&Bbuf[(brow0 + nt * 16) * 64 + sc];
#pragma unroll
      for (int mt = 0; mt < 3; mt++)
#pragma unroll
        for (int nt = 0; nt < 6; nt++)
          acc[mt][nt] = __builtin_amdgcn_mfma_f32_16x16x32_bf16(
              af[mt], bfr[nt], acc[mt][nt], 0, 0, 0);
    }
  }

  __syncthreads();
  const int crow0 = wm * 48 + ((lane >> 4) << 2);
  const int ccol0 = wn * 96 + (lane & 15);
#pragma unroll
  for (int nt = 0; nt < 6; nt++) {
    const int col = ccol0 + nt * 16;
    const float bv = bin[(col >> 6) * 512 + h * 64 + (col & 63)];
#pragma unroll
    for (int mt = 0; mt < 3; mt++) {
      const int rb = (crow0 + mt * 16) * 200 + col;
      const unsigned p01 = pack2bf(acc[mt][nt][0] + bv, acc[mt][nt][1] + bv);
      const unsigned p23 = pack2bf(acc[mt][nt][2] + bv, acc[mt][nt][3] + bv);
      lds[rb]       = (unsigned short)p01;
      lds[rb + 200] = (unsigned short)(p01 >> 16);
      lds[rb + 400] = (unsigned short)p23;
      lds[rb + 600] = (unsigned short)(p23 >> 16);
    }
  }
  __syncthreads();

  const int bi = lane >> 3;
  const int l8 = lane & 7;
  const int r0 = (wave * 8 + bi) * 3;
  float q[3][8], k[3][8], v[3][8];
#pragma unroll
  for (int s = 0; s < 3; s++) {
    const unsigned short* rowp = &lds[(r0 + s) * 200 + l8 * 8];
    uint4 qu = *(const uint4*)(rowp);
    uint4 ku = *(const uint4*)(rowp + 64);
    uint4 vu = *(const uint4*)(rowp + 128);
    const unsigned* qw = (const unsigned*)&qu;
    const unsigned* kw = (const unsigned*)&ku;
    const unsigned* vw = (const unsigned*)&vu;
#pragma unroll
    for (int jj = 0; jj < 4; jj++) {
      q[s][2 * jj]     = __uint_as_float(qw[jj] << 16);
      q[s][2 * jj + 1] = __uint_as_float(qw[jj] & 0xffff0000u);
      k[s][2 * jj]     = __uint_as_float(kw[jj] << 16);
      k[s][2 * jj + 1] = __uint_as_float(kw[jj] & 0xffff0000u);
      v[s][2 * jj]     = __uint_as_float(vw[jj] << 16);
      v[s][2 * jj + 1] = __uint_as_float(vw[jj] & 0xffff0000u);
    }
  }
  float p[3][3];
#pragma unroll
  for (int s = 0; s < 3; s++)
#pragma unroll
    for (int u = 0; u < 3; u++) {
      float d = 0.f;
#pragma unroll
      for (int e = 0; e < 8; e++) d = fmaf(q[s][e], k[u][e], d);
      p[s][u] = d;
    }
#pragma unroll
  for (int m = 1; m < 8; m <<= 1)
#pragma unroll
    for (int s = 0; s < 3; s++)
#pragma unroll
      for (int u = 0; u < 3; u++) p[s][u] += __shfl_xor(p[s][u], m, 64);

  unsigned short* ob = AO + (m0 + r0) * 512 + h * 64 + l8 * 8;
#pragma unroll
  for (int s = 0; s < 3; s++) {
    float a0 = p[s][0] * 0.125f, a1 = p[s][1] * 0.125f, a2 = p[s][2] * 0.125f;
    float mx = fmaxf(a0, fmaxf(a1, a2));
    float e0 = __expf(a0 - mx), e1 = __expf(a1 - mx), e2 = __expf(a2 - mx);
    float inv = 1.0f / (e0 + e1 + e2);
    unsigned ow[4];
#pragma unroll
    for (int jj = 0; jj < 4; jj++) {
      float lo = (e0 * v[0][2 * jj] + e1 * v[1][2 * jj] + e2 * v[2][2 * jj]) * inv;
      float hi = (e0 * v[0][2 * jj + 1] + e1 * v[1][2 * jj + 1] + e2 * v[2][2 * jj + 1]) * inv;
      ow[jj] = pack2bf(lo, hi);
    }
    *(uint4*)(ob + s * 512) = *(uint4*)ow;
  }
}

// ---------------------------------------------------------------- GEMM (128x128 2-phase)
enum { EPI_BF16 = 0, EPI_RES = 1, EPI_SILU = 2, EPI_F32 = 3 };

template <int EPI>
__global__ void __launch_bounds__(256)
gemm_bt(const unsigned short* __restrict__ A,
        const unsigned short* __restrict__ W,
        const float* __restrict__ bias,
        const unsigned short* __restrict__ Res,
        void* __restrict__ Out,
        int K, int N) {
  __shared__ unsigned short As[128 * 64];
  __shared__ unsigned short Bs[128 * 64];
  const int t = threadIdx.x;
  const int lane = t & 63;
  const int wave = t >> 6;
  const int wm = wave >> 1, wn = wave & 1;

  const int nb = gridDim.x;
  const int nblocks = nb * gridDim.y;
  const int id = blockIdx.y * nb + blockIdx.x;
  const int lid = ((nblocks & 7) == 0) ? ((id & 7) * (nblocks >> 3) + (id >> 3)) : id;
  const long bm = (long)(lid / nb) * 128;
  const long bn = (long)(lid % nb) * 128;

  const int srow = t >> 3;
  const int schunk = ((t & 7) ^ (srow & 7)) << 3;
  const unsigned short* Ag = A + (bm + srow) * (long)K + schunk;
  const unsigned short* Wg = W + (bn + srow) * (long)K + schunk;
  unsigned short* AsD = As + t * 8;
  unsigned short* BsD = Bs + t * 8;

  f32x4 acc[4][4] = {};
  const int arow0 = wm * 64 + (lane & 15);
  const int brow0 = wn * 64 + (lane & 15);

  for (int k0 = 0; k0 < K; k0 += 64) {
    __syncthreads();
#pragma unroll
    for (int i = 0; i < 4; i++) {
      async_cp16(Ag + (long)(i * 32) * K + k0, AsD + i * 2048);
      async_cp16(Wg + (long)(i * 32) * K + k0, BsD + i * 2048);
    }
    __syncthreads();
#pragma unroll
    for (int kk = 0; kk < 2; kk++) {
      const int sc = ((kk * 4 + (lane >> 4)) ^ (lane & 7)) << 3;
      bf16x8 af[4], bfr[4];
#pragma unroll
      for (int mt = 0; mt < 4; mt++)
        af[mt] = *(const bf16x8*)&As[(arow0 + mt * 16) * 64 + sc];
#pragma unroll
      for (int nt = 0; nt < 4; nt++)
        bfr[nt] = *(const bf16x8*)&Bs[(brow0 + nt * 16) * 64 + sc];
#pragma unroll
      for (int mt = 0; mt < 4; mt++)
#pragma unroll
        for (int nt = 0; nt < 4; nt++)
          acc[mt][nt] = __builtin_amdgcn_mfma_f32_16x16x32_bf16(
              af[mt], bfr[nt], acc[mt][nt], 0, 0, 0);
    }
  }

  const long row0 = bm + wm * 64 + ((lane >> 4) << 2);
  const int col0 = (int)bn + wn * 64 + (lane & 15);
#pragma unroll
  for (int nt = 0; nt < 4; nt++) {
    const int col = col0 + nt * 16;
    const float bv = bias[col];
#pragma unroll
    for (int mt = 0; mt < 4; mt++) {
      const long rbase = row0 + mt * 16;
#pragma unroll
      for (int r = 0; r < 4; r++) {
        float v = acc[mt][nt][r] + bv;
        const long idx = (rbase + r) * (long)N + col;
        if (EPI == EPI_RES) v += bf2f(Res[idx]);
        if (EPI == EPI_SILU) v = v * (1.0f / (1.0f + __expf(-v)));
        if (EPI == EPI_F32)
          ((float*)Out)[idx] = v;
        else
          ((unsigned short*)Out)[idx] = f2bf(v);
      }
    }
  }
}

// ---------------------------------------------------------------- SILU GEMM, 256x256 8-phase pipeline
// H = silu(G[32768,1536] @ w1[1024,1536]^T + b1), bf16 out.
// 8 waves (2Mx4N), per-wave 128x64 = acc[8][4]. LDS 128 KiB: A/B each
// [2 dbuf][2 khalf][256 rows][32 k] bf16; half-tile = 16 KB = 2 cp16/thread.
// Swizzle: phys_chunk = c ^ ((row>>1)&3) (2 lanes/bank on ds_read_b128).
// Tile t phases: p1 kh0/mt0-3(+B kh0, held), p2 kh0/mt4-7, p3 kh1/mt0-3
// (+B kh1), p4 kh1/mt4-7. Stages: p1 A-kk1(t+1), p2 B-kk1(t+1),
// p3 A-kk0(t+2, same dbuf: region's last read was p2), p4 B-kk0(t+2).
// vmcnt(8) at p2/p4 end only (max 12 in flight -> forces 4-phase-old stages
// complete); barrier after makes the guarantee block-wide.
__global__ void __launch_bounds__(512)
gemm_silu256(const unsigned short* __restrict__ A,   // [32768,1536] bf16
             const unsigned short* __restrict__ W,   // [1024,1536] bf16
             const float* __restrict__ bias,         // [1024]
             unsigned short* __restrict__ Out) {     // [32768,1024] bf16
  constexpr int K = 1536, N = 1024, NT = 24;
  constexpr int NSH = 8192, NDB = 16384;     // elems per khalf / per dbuf
  __shared__ unsigned short As[2 * NDB];     // 64 KB
  __shared__ unsigned short Bs[2 * NDB];     // 64 KB
  const int t = threadIdx.x;
  const int lane = t & 63;
  const int wave = t >> 6;
  const int wm = wave >> 2, wn = wave & 3;
  const int l15 = lane & 15, lg = lane >> 4;

  const int nb = gridDim.x;                  // 4
  const int nblocks = nb * gridDim.y;        // 512
  const int id = blockIdx.y * nb + blockIdx.x;
  const int lid = (id & 7) * (nblocks >> 3) + (id >> 3);
  const long bm = (long)(lid / nb) * 256;
  const long bn = (long)(lid % nb) * 256;

  // stage source: chunk ci=t (rows 0-127) and ci=t+512 (rows 128-255);
  // logical chunk = phys ^ ((row>>1)&3)  (pre-swizzled source, linear dest)
  const int r0s = t >> 2, pc = t & 3;
  const int c0 = pc ^ ((r0s >> 1) & 3);
  const int r1s = r0s + 128;
  const int c1 = pc ^ ((r1s >> 1) & 3);
  const unsigned short* Ag0 = A + (bm + r0s) * (long)K + c0 * 8;
  const unsigned short* Ag1 = A + (bm + r1s) * (long)K + c1 * 8;
  const unsigned short* Wg0 = W + (bn + r0s) * (long)K + c0 * 8;
  const unsigned short* Wg1 = W + (bn + r1s) * (long)K + c1 * 8;

#define STA(d, kh, kb) do { \
    async_cp16(Ag0 + (kb), &As[(d) * NDB + (kh) * NSH + t * 8]); \
    async_cp16(Ag1 + (kb), &As[(d) * NDB + (kh) * NSH + 4096 + t * 8]); } while (0)
#define STB(d, kh, kb) do { \
    async_cp16(Wg0 + (kb), &Bs[(d) * NDB + (kh) * NSH + t * 8]); \
    async_cp16(Wg1 + (kb), &Bs[(d) * NDB + (kh) * NSH + 4096 + t * 8]); } while (0)

  // frag read offsets (xor key depends only on l15 since 16|row-base)
  const int ach = (lg ^ ((l15 >> 1) & 3)) << 3;
  const int aoff = (wm * 128 + l15) * 32 + ach;
  const int boff = (wn * 64 + l15) * 32 + ach;

  f32x4 acc[8][4] = {};

  // prologue: kk0(t0), kk1(t0), kk0(t1) staged; ensure kk0(t0) landed
  STA(0, 0, 0);  STB(0, 0, 0);
  STA(0, 1, 32); STB(0, 1, 32);
  STA(1, 0, 64); STB(1, 0, 64);
  asm volatile("s_waitcnt vmcnt(8)" ::: "memory");
  __builtin_amdgcn_s_barrier();

  for (int tt = 0; tt < NT; ++tt) {
    const int d = tt & 1, dn = d ^ 1;
    const bool s1 = (tt + 1 < NT), s2 = (tt + 2 < NT);
    const int kb1 = (tt + 1) * 64, kb2 = (tt + 2) * 64;
    const unsigned short* Ab = &As[d * NDB];
    const unsigned short* Bb = &Bs[d * NDB];
    bf16x8 af[4], bfr[4];

    // p1: kh0, mt0-3 (+B kh0); stage A-kk1(t+1)
#pragma unroll
    for (int i = 0; i < 4; ++i) af[i] = *(const bf16x8*)&Ab[aoff + i * 512];
#pragma unroll
    for (int i = 0; i < 4; ++i) bfr[i] = *(const bf16x8*)&Bb[boff + i * 512];
    if (s1) STA(dn, 1, kb1 + 32);
    __builtin_amdgcn_s_barrier();
    asm volatile("s_waitcnt lgkmcnt(0)" ::: "memory");
    __builtin_amdgcn_s_setprio(1);
#pragma unroll
    for (int mi = 0; mi < 4; ++mi)
#pragma unroll
      for (int ni = 0; ni < 4; ++ni)
        acc[mi][ni] = __builtin_amdgcn_mfma_f32_16x16x32_bf16(
            af[mi], bfr[ni], acc[mi][ni], 0, 0, 0);
    __builtin_amdgcn_s_setprio(0);
    __builtin_amdgcn_s_barrier();

    // p2: kh0, mt4-7 (B held); stage B-kk1(t+1)
#pragma unroll
    for (int i = 0; i < 4; ++i) af[i] = *(const bf16x8*)&Ab[aoff + (4 + i) * 512];
    if (s1) STB(dn, 1, kb1 + 32);
    __builtin_amdgcn_s_barrier();
    asm volatile("s_waitcnt lgkmcnt(0)" ::: "memory");
    __builtin_amdgcn_s_setprio(1);
#pragma unroll
    for (int mi = 0; mi < 4; ++mi)
#pragma unroll
      for (int ni = 0; ni < 4; ++ni)
        acc[4 + mi][ni] = __builtin_amdgcn_mfma_f32_16x16x32_bf16(
            af[mi], bfr[ni], acc[4 + mi][ni], 0, 0, 0);
    __builtin_amdgcn_s_setprio(0);
    asm volatile("s_waitcnt vmcnt(8)" ::: "memory");
    __builtin_amdgcn_s_barrier();

    // p3: kh1, mt0-3 (+B kh1); stage A-kk0(t+2) into dbuf d (region retired @p2)
#pragma unroll
    for (int i = 0; i < 4; ++i) af[i] = *(const bf16x8*)&Ab[NSH + aoff + i * 512];
#pragma unroll
    for (int i = 0; i < 4; ++i) bfr[i] = *(const bf16x8*)&Bb[NSH + boff + i * 512];
    if (s2) STA(d, 0, kb2);
    __builtin_amdgcn_s_barrier();
    asm volatile("s_waitcnt lgkmcnt(0)" ::: "memory");
    __builtin_amdgcn_s_setprio(1);
#pragma unroll
    for (int mi = 0; mi < 4; ++mi)
#pragma unroll
      for (int ni = 0; ni < 4; ++ni)
        acc[mi][ni] = __builtin_amdgcn_mfma_f32_16x16x32_bf16(
            af[mi], bfr[ni], acc[mi][ni], 0, 0, 0);
    __builtin_amdgcn_s_setprio(0);
    __builtin_amdgcn_s_barrier();

    // p4: kh1, mt4-7 (B held); stage B-kk0(t+2)
#pragma unroll
    for (int i = 0; i < 4; ++i) af[i] = *(const bf16x8*)&Ab[NSH + aoff + (4 + i) * 512];
    if (s2) STB(d, 0, kb2);
    __builtin_amdgcn_s_barrier();
    asm volatile("s_waitcnt lgkmcnt(0)" ::: "memory");
    __builtin_amdgcn_s_setprio(1);
#pragma unroll
    for (int mi = 0; mi < 4; ++mi)
#pragma unroll
      for (int ni = 0; ni < 4; ++ni)
        acc[4 + mi][ni] = __builtin_amdgcn_mfma_f32_16x16x32_bf16(
            af[mi], bfr[ni], acc[4 + mi][ni], 0, 0, 0);
    __builtin_amdgcn_s_setprio(0);
    asm volatile("s_waitcnt vmcnt(8)" ::: "memory");
    __builtin_amdgcn_s_barrier();
  }
#undef STA
#undef STB

  // epilogue: bias + SILU + bf16 store
  const long grow0 = bm + wm * 128 + (lg << 2);
  const int col0 = (int)bn + wn * 64 + l15;
#pragma unroll
  for (int nt = 0; nt < 4; ++nt) {
    const int col = col0 + nt * 16;
    const float bv = bias[col];
#pragma unroll
    for (int mt = 0; mt < 8; ++mt) {
      const long rb = grow0 + mt * 16;
#pragma unroll
      for (int r = 0; r < 4; ++r) {
        float v = acc[mt][nt][r] + bv;
        v = v * (1.0f / (1.0f + __expf(-v)));
        Out[(rb + r) * (long)N + col] = f2bf(v);
      }
    }
  }
}

// ---------------------------------------------------------------- GEMM + LayerNorm fused
__global__ void __launch_bounds__(512)
gemm_ln(const unsigned short* __restrict__ A,    // [M,1024] bf16
        const unsigned short* __restrict__ W,    // [512,1024] bf16
        const float* __restrict__ bias,          // [512]
        const float* __restrict__ gamma,         // [512]
        const float* __restrict__ beta,          // [512]
        float* __restrict__ Out,                 // [M,512] f32
        int K) {
  __shared__ unsigned short As[64 * 64];
  __shared__ unsigned short Bs[512 * 64];
  __shared__ float stats[8][64][2];
  const int t = threadIdx.x;
  const int lane = t & 63;
  const int wave = t >> 6;

  const int nblocks = gridDim.x;
  const int id = blockIdx.x;
  const int lid = ((nblocks & 7) == 0) ? ((id & 7) * (nblocks >> 3) + (id >> 3)) : id;
  const long bm = (long)lid * 64;

  const int srow = t >> 3;
  const int sch = ((t & 7) ^ (srow & 7)) << 3;
  const unsigned short* Ag = A + (bm + srow) * (long)K + sch;
  const unsigned short* Wg = W + (long)srow * K + sch;
  unsigned short* AsD = As + t * 8;
  unsigned short* BsD = Bs + t * 8;

  f32x4 acc[4][4] = {};
  const int arow0 = lane & 15;
  const int brow0 = wave * 64 + (lane & 15);

  for (int k0 = 0; k0 < K; k0 += 64) {
    __syncthreads();
    async_cp16(Ag + k0, AsD);
#pragma unroll
    for (int i = 0; i < 8; i++)
      async_cp16(Wg + (long)(i * 64) * K + k0, BsD + i * 4096);
    __syncthreads();
#pragma unroll
    for (int kk = 0; kk < 2; kk++) {
      const int sc = ((kk * 4 + (lane >> 4)) ^ (lane & 7)) << 3;
      bf16x8 af[4], bfr[4];
#pragma unroll
      for (int mt = 0; mt < 4; mt++)
        af[mt] = *(const bf16x8*)&As[(arow0 + mt * 16) * 64 + sc];
#pragma unroll
      for (int nt = 0; nt < 4; nt++)
        bfr[nt] = *(const bf16x8*)&Bs[(brow0 + nt * 16) * 64 + sc];
#pragma unroll
      for (int mt = 0; mt < 4; mt++)
#pragma unroll
        for (int nt = 0; nt < 4; nt++)
          acc[mt][nt] = __builtin_amdgcn_mfma_f32_16x16x32_bf16(
              af[mt], bfr[nt], acc[mt][nt], 0, 0, 0);
    }
  }

  const int colb = wave * 64 + (lane & 15);
  float bv[4], gm[4], be[4];
#pragma unroll
  for (int nt = 0; nt < 4; nt++) {
    bv[nt] = bias[colb + nt * 16];
    gm[nt] = gamma[colb + nt * 16];
    be[nt] = beta[colb + nt * 16];
  }
#pragma unroll
  for (int mt = 0; mt < 4; mt++)
#pragma unroll
    for (int r = 0; r < 4; r++) {
      float s = 0.f, ss = 0.f;
#pragma unroll
      for (int nt = 0; nt < 4; nt++) {
        const float v = acc[mt][nt][r] + bv[nt];
        s += v; ss += v * v;
      }
#pragma unroll
      for (int m = 1; m < 16; m <<= 1) {
        s += __shfl_xor(s, m, 64);
        ss += __shfl_xor(ss, m, 64);
      }
      if ((lane & 15) == 0) {
        const int rl = mt * 16 + ((lane >> 4) << 2) + r;
        stats[wave][rl][0] = s;
        stats[wave][rl][1] = ss;
      }
    }
  __syncthreads();
#pragma unroll
  for (int mt = 0; mt < 4; mt++)
#pragma unroll
    for (int r = 0; r < 4; r++) {
      const int rl = mt * 16 + ((lane >> 4) << 2) + r;
      float s = 0.f, ss = 0.f;
#pragma unroll
      for (int w = 0; w < 8; w++) {
        s += stats[w][rl][0];
        ss += stats[w][rl][1];
      }
      const float mean = s * (1.0f / 512.0f);
      const float var = ss * (1.0f / 512.0f) - mean * mean;
      const float rstd = rsqrtf(var + 1e-5f);
      float* orow = Out + (bm + rl) * 512;
#pragma unroll
      for (int nt = 0; nt < 4; nt++) {
        const float v = acc[mt][nt][r] + bv[nt];
        orow[colb + nt * 16] = (v - mean) * rstd * gm[nt] + be[nt];
      }
    }
}

// ---------------------------------------------------------------- gate
__global__ void __launch_bounds__(256) gate3(const unsigned short* AT,
                                             const float* __restrict__ WG,
                                             const float* __restrict__ BG,
                                             unsigned short* G) {
  int row = blockIdx.x * 4 + (threadIdx.x >> 6);
  int lane = threadIdx.x & 63;
  const unsigned short* rp = AT + (long)row * 1536 + lane * 8;
  float x[3][8];
  float p[3] = {0.f, 0.f, 0.f};
#pragma unroll
  for (int seg = 0; seg < 3; seg++) {
    uint4 u = *(const uint4*)(rp + seg * 512);
    const unsigned* uw = (const unsigned*)&u;
#pragma unroll
    for (int j = 0; j < 4; j++) {
      x[seg][2 * j]     = __uint_as_float(uw[j] << 16);
      x[seg][2 * j + 1] = __uint_as_float(uw[j] & 0xffff0000u);
    }
    const int e0 = seg * 512 + lane * 8;
#pragma unroll
    for (int g = 0; g < 3; g++) {
      const float* wp = WG + g * 1536 + e0;
#pragma unroll
      for (int e = 0; e < 8; e++) p[g] = fmaf(x[seg][e], wp[e], p[g]);
    }
  }
#pragma unroll
  for (int m = 1; m < 64; m <<= 1)
#pragma unroll
    for (int g = 0; g < 3; g++) p[g] += __shfl_xor(p[g], m, 64);
  float g0 = p[0] + BG[0], g1 = p[1] + BG[1], g2 = p[2] + BG[2];
  float mx = fmaxf(g0, fmaxf(g1, g2));
  g0 = __expf(g0 - mx); g1 = __expf(g1 - mx); g2 = __expf(g2 - mx);
  float inv = 1.0f / (g0 + g1 + g2);
  float gs[3] = {g0 * inv, g1 * inv, g2 * inv};
  unsigned short* op = G + (long)row * 1536 + lane * 8;
#pragma unroll
  for (int seg = 0; seg < 3; seg++) {
    unsigned ow[4];
#pragma unroll
    for (int j = 0; j < 4; j++)
      ow[j] = pack2bf(x[seg][2 * j] * gs[seg], x[seg][2 * j + 1] * gs[seg]);
    *(uint4*)(op + seg * 512) = *(uint4*)ow;
  }
}

// ---------------------------------------------------------------- launch
extern "C" void kernel_launch(void* const* d_in, const int* in_sizes, int n_in,
                              void* d_out, int out_size, void* d_ws, size_t ws_size,
                              hipStream_t stream) {
  const float* kin    = (const float*)d_in[0];
  const float* colr   = (const float*)d_in[1];
  const float* spi    = (const float*)d_in[2];
  const float* w_in   = (const float*)d_in[3];
  const float* b_in   = (const float*)d_in[4];
  const float* w_out  = (const float*)d_in[5];
  const float* b_out  = (const float*)d_in[6];
  const float* w_gate = (const float*)d_in[7];
  const float* b_gate = (const float*)d_in[8];
  const float* w1     = (const float*)d_in[9];
  const float* b1     = (const float*)d_in[10];
  const float* w2     = (const float*)d_in[11];
  const float* b2     = (const float*)d_in[12];
  const float* gamma  = (const float*)d_in[13];
  const float* beta   = (const float*)d_in[14];
  float* out = (float*)d_out;

  long Bc = 32768;
  while (Bc > 1024 && (size_t)(6291456 + 9216 * Bc) > ws_size) Bc >>= 1;
  const int nch = (int)(32768 / Bc);

  char* ws = (char*)d_ws;
  unsigned short* Wic = (unsigned short*)(ws);              // w_in  1536x512
  unsigned short* Woc = (unsigned short*)(ws + 1572864);    // w_out 512x512
  unsigned short* W1c = (unsigned short*)(ws + 2097152);    // w1    1024x1536
  unsigned short* W2c = (unsigned short*)(ws + 5242880);    // w2    512x1024
  char* Sb  = ws + 6291456;                                 // S  [3Bc,512] bf16
  char* AOb = Sb + 3072 * Bc;                               // AO [3Bc,512] bf16
  char* ATb = AOb + 3072 * Bc;                              // AT [3Bc,512] bf16

  cvtall<<<3072, 256, 0, stream>>>((const float4*)w_in, (const float4*)w_out,
                                   (const float4*)w1, (const float4*)w2,
                                   (uint2*)ws);

  for (int c = 0; c < nch; c++) {
    const long boff = (long)c * Bc;
    unsigned short* S_c  = (unsigned short*)Sb;
    unsigned short* AO_c = (unsigned short*)AOb;
    unsigned short* AT_c = (unsigned short*)ATb;
    unsigned short* G_c  = AT_c;                   // gate in-place
    unsigned short* H_c  = (unsigned short*)AOb;   // [Bc,1024], AO dead after proj

    // fused pack + qkv-gemm + attention: f32 inputs -> AO (+ S side-product)
    qkv_attn<<<dim3(8, (int)(Bc / 32)), 256, 0, stream>>>(
        kin + boff * 512, colr + boff * 512, spi + boff * 512,
        Wic, b_in, S_c, AO_c);
    // attn_out = S + AO @ w_out^T + b_out   M=3Bc N=512 K=512
    gemm_bt<EPI_RES><<<dim3(4, (int)(3 * Bc / 128)), 256, 0, stream>>>(
        AO_c, Woc, b_out, S_c, AT_c, 512, 512);
    gate3<<<(int)(Bc / 4), 256, 0, stream>>>(AT_c, w_gate, b_gate, G_c);
    // h = silu(G @ w1^T + b1)  M=Bc N=1024 K=1536 — 8-phase 256^2 pipeline
    gemm_silu256<<<dim3(4, (int)(Bc / 256)), 512, 0, stream>>>(
        G_c, W1c, b1, H_c);
    // out = LN(h @ w2^T + b2)           M=Bc N=512 K=1024, fused layernorm
    gemm_ln<<<(int)(Bc / 64), 512, 0, stream>>>(
        H_c, W2c, b2, gamma, beta, out + boff * 512, 1024);
  }
}